// Round 12
// baseline (187.478 us; speedup 1.0000x reference)
//
#include <hip/hip_runtime.h>
#include <math.h>

#define B_ 1024
#define G_ 256
#define K_ 256
#define E_ 64
#define D_CH 8    // Chebyshev degree (branch point ~lambda=-5 -> ~13^-j decay)
#define LP 40     // g1 LDS pitch (ushorts) for 32-g chunks
#define WP 72     // pre LDS pitch (ushorts)

// ws layout (floats)
#define OFF_Q6  ((size_t)0)                          // K*E*E = 1048576
#define OFF_V   ((size_t)1048576)                    // K*E
#define OFF_VT  ((size_t)1064960)                    // K*E
#define OFF_MSQ ((size_t)1081344)                    // K
#define OFF_SC  ((size_t)1081600)                    // K*B (TRANSPOSED: [k][b])
#define OFF_U16 ((size_t)1343744)                    // ushort area (16B aligned)
#define U_WTH  ((size_t)0)           // K*80*256
#define U_WTL  ((size_t)5242880)
#define U_IMGH ((size_t)10485760)    // B*G
#define U_IMGL ((size_t)10747904)

typedef short v8s __attribute__((ext_vector_type(8)));
typedef float v4f __attribute__((ext_vector_type(4)));

struct Cheb { float cF[D_CH + 1]; float cQ[D_CH + 1]; float alpha; float gamma; };

__device__ __forceinline__ unsigned short bf16_rne(float x) {
    unsigned int u = __float_as_uint(x);
    unsigned int r = (u + 0x7FFFu + ((u >> 16) & 1u)) >> 16;
    return (unsigned short)r;
}
__device__ __forceinline__ float bf16_to_f(unsigned short h) {
    return __uint_as_float(((unsigned int)h) << 16);
}

// ---------------------------------------------------------------------------
// pre (MFMA): grid K, block 256 (4 waves). Wave w owns column slab [w*16,w*16+16).
// Barrier-free Chebyshev recurrence. Fused img hi/lo split at kernel start.
// Phase-A staging: column loads + packed b128 LDS writes (was 32 scalar u16).
__global__ __launch_bounds__(256, 1) void pre_kernel(const float* __restrict__ img,
                                                     const float* __restrict__ w,
                                                     const float* __restrict__ mu,
                                                     float* __restrict__ ws, Cheb cf) {
    const int k = blockIdx.x;
    const int t = threadIdx.x;
    const int wid = t >> 6;
    const int lane = t & 63;
    const int c = lane & 15, q = lane >> 4;
    const int n_ = wid * 16 + c;

    __shared__ __align__(16) unsigned short sXH[64 * WP];
    __shared__ __align__(16) unsigned short sXL[64 * WP];
    __shared__ __align__(16) unsigned short sTH[8 * 16 * WP];
    __shared__ __align__(16) unsigned short sTL[8 * 16 * WP];
    __shared__ float sMu[64];
    __shared__ float sV[64];
    __shared__ float dred[256];

    unsigned short* wsu = (unsigned short*)(ws + OFF_U16);
    unsigned short* wtTH = wsu + U_WTH;
    unsigned short* wtTL = wsu + U_WTL;

    // ---- fused img split: 1 float4 per thread ----
    {
        unsigned short* imgH = wsu + U_IMGH;
        unsigned short* imgL = wsu + U_IMGL;
        int i = k * 256 + t;
        float4 x = ((const float4*)img)[i];
        ushort4 h, l;
        h.x = bf16_rne(x.x); l.x = bf16_rne(x.x - bf16_to_f(h.x));
        h.y = bf16_rne(x.y); l.y = bf16_rne(x.y - bf16_to_f(h.y));
        h.z = bf16_rne(x.z); l.z = bf16_rne(x.z - bf16_to_f(h.z));
        h.w = bf16_rne(x.w); l.w = bf16_rne(x.w - bf16_to_f(h.w));
        ((ushort4*)imgH)[i] = h;
        ((ushort4*)imgL)[i] = l;
    }

    v4f accA[4];
#pragma unroll
    for (int mi = 0; mi < 4; ++mi) accA[mi] = (v4f){0.f, 0.f, 0.f, 0.f};
    float vacc = 0.f, msqacc = 0.f;

    for (int gc = 0; gc < 4; ++gc) {
        __syncthreads();
        // stage trW chunk [e][g]: thread = (e = t&63, g0 = wid*16), 16 coalesced
        // column loads, packed 16B LDS writes.
        {
            const int e = t & 63;
            const int g0 = (t >> 6) * 16;
            unsigned int hp[8], lp[8];
#pragma unroll
            for (int j = 0; j < 8; ++j) {
                float x0 = w[((size_t)k * G_ + gc * 64 + g0 + 2 * j) * 64 + e];
                float x1 = w[((size_t)k * G_ + gc * 64 + g0 + 2 * j + 1) * 64 + e];
                unsigned short h0 = bf16_rne(x0);
                unsigned short l0 = bf16_rne(x0 - bf16_to_f(h0));
                unsigned short h1 = bf16_rne(x1);
                unsigned short l1 = bf16_rne(x1 - bf16_to_f(h1));
                hp[j] = (unsigned int)h0 | ((unsigned int)h1 << 16);
                lp[j] = (unsigned int)l0 | ((unsigned int)l1 << 16);
            }
            uint4 u0 = make_uint4(hp[0], hp[1], hp[2], hp[3]);
            uint4 u1 = make_uint4(hp[4], hp[5], hp[6], hp[7]);
            uint4 v0 = make_uint4(lp[0], lp[1], lp[2], lp[3]);
            uint4 v1 = make_uint4(lp[4], lp[5], lp[6], lp[7]);
            *(uint4*)&sTH[e * WP + g0] = u0;
            *(uint4*)&sTH[e * WP + g0 + 8] = u1;
            *(uint4*)&sTL[e * WP + g0] = v0;
            *(uint4*)&sTL[e * WP + g0 + 8] = v1;
        }
        if (t < 64) {
            float m = mu[(size_t)(gc * 64 + t) * K_ + k];
            sMu[t] = m;
            unsigned short h = bf16_rne(m);
            unsigned short l = bf16_rne(m - bf16_to_f(h));
            size_t gcol = ((size_t)k * 80 + 64) * 256 + gc * 64 + t;
            wtTH[gcol] = h;
            wtTL[gcol] = l;
        }
        __syncthreads();
#pragma unroll
        for (int kc = 0; kc < 2; ++kc) {
            v8s bH = *(const v8s*)&sTH[(wid * 16 + c) * WP + kc * 32 + q * 8];
            v8s bL = *(const v8s*)&sTL[(wid * 16 + c) * WP + kc * 32 + q * 8];
#pragma unroll
            for (int mi = 0; mi < 4; ++mi) {
                v8s aH = *(const v8s*)&sTH[(mi * 16 + c) * WP + kc * 32 + q * 8];
                v8s aL = *(const v8s*)&sTL[(mi * 16 + c) * WP + kc * 32 + q * 8];
                accA[mi] = __builtin_amdgcn_mfma_f32_16x16x32_bf16(aH, bH, accA[mi], 0, 0, 0);
                accA[mi] = __builtin_amdgcn_mfma_f32_16x16x32_bf16(aH, bL, accA[mi], 0, 0, 0);
                accA[mi] = __builtin_amdgcn_mfma_f32_16x16x32_bf16(aL, bH, accA[mi], 0, 0, 0);
            }
        }
        for (int gg = wid * 16; gg < wid * 16 + 16; ++gg) {
            float rec = bf16_to_f(sTH[lane * WP + gg]) + bf16_to_f(sTL[lane * WP + gg]);
            vacc += rec * sMu[gg];
        }
        if (t == 255) {
            for (int gg = 0; gg < 64; ++gg) msqacc += sMu[gg] * sMu[gg];
        }
    }
    dred[t] = vacc;
    if (t == 255) ws[OFF_MSQ + k] = msqacc;
    __syncthreads();
    if (t < 64) {
        float v = dred[t] + dred[t + 64] + dred[t + 128] + dred[t + 192];
        sV[t] = v;
        ws[OFF_V + (size_t)k * 64 + t] = v;
    }

    v4f Tcur[4], Told[4], Facc[4], Qacc[4];
#pragma unroll
    for (int mi = 0; mi < 4; ++mi) {
        ushort4 hv, lv;
        float xr[4];
#pragma unroll
        for (int r = 0; r < 4; ++r) {
            int m = mi * 16 + q * 4 + r;
            float id = (m == n_) ? 1.f : 0.f;
            float xv = cf.alpha * accA[mi][r] + cf.gamma * id;
            xr[r] = xv;
            Tcur[mi][r] = xv;
            Told[mi][r] = id;
            Facc[mi][r] = cf.cF[0] * id + cf.cF[1] * xv;
            Qacc[mi][r] = cf.cQ[0] * id + cf.cQ[1] * xv;
        }
        hv.x = bf16_rne(xr[0]); lv.x = bf16_rne(xr[0] - bf16_to_f(hv.x));
        hv.y = bf16_rne(xr[1]); lv.y = bf16_rne(xr[1] - bf16_to_f(hv.y));
        hv.z = bf16_rne(xr[2]); lv.z = bf16_rne(xr[2] - bf16_to_f(hv.z));
        hv.w = bf16_rne(xr[3]); lv.w = bf16_rne(xr[3] - bf16_to_f(hv.w));
        *(ushort4*)&sXH[n_ * WP + mi * 16 + q * 4] = hv;
        *(ushort4*)&sXL[n_ * WP + mi * 16 + q * 4] = lv;
    }
    __syncthreads();
    v8s xaH[4][2], xaL[4][2];
#pragma unroll
    for (int mi = 0; mi < 4; ++mi)
#pragma unroll
        for (int kc = 0; kc < 2; ++kc) {
            xaH[mi][kc] = *(const v8s*)&sXH[(mi * 16 + c) * WP + kc * 32 + q * 8];
            xaL[mi][kc] = *(const v8s*)&sXL[(mi * 16 + c) * WP + kc * 32 + q * 8];
        }

#pragma unroll
    for (int j = 2; j <= D_CH; ++j) {
        const unsigned short* sH =
            (j == 2) ? &sXH[(wid * 16) * WP] : &sTH[((((j - 1) & 1)) * 4 + wid) * 16 * WP];
        const unsigned short* sL =
            (j == 2) ? &sXL[(wid * 16) * WP] : &sTL[((((j - 1) & 1)) * 4 + wid) * 16 * WP];
        unsigned short* dH = &sTH[((j & 1) * 4 + wid) * 16 * WP];
        unsigned short* dL = &sTL[((j & 1) * 4 + wid) * 16 * WP];
        v8s tbH[2], tbL[2];
#pragma unroll
        for (int kc = 0; kc < 2; ++kc) {
            tbH[kc] = *(const v8s*)&sH[c * WP + kc * 32 + q * 8];
            tbL[kc] = *(const v8s*)&sL[c * WP + kc * 32 + q * 8];
        }
#pragma unroll
        for (int mi = 0; mi < 4; ++mi) {
            v4f gt = (v4f){0.f, 0.f, 0.f, 0.f};
#pragma unroll
            for (int kc = 0; kc < 2; ++kc) {
                gt = __builtin_amdgcn_mfma_f32_16x16x32_bf16(xaH[mi][kc], tbH[kc], gt, 0, 0, 0);
                gt = __builtin_amdgcn_mfma_f32_16x16x32_bf16(xaH[mi][kc], tbL[kc], gt, 0, 0, 0);
                gt = __builtin_amdgcn_mfma_f32_16x16x32_bf16(xaL[mi][kc], tbH[kc], gt, 0, 0, 0);
            }
            v4f tn = 2.f * gt - Told[mi];
            Told[mi] = Tcur[mi];
            Tcur[mi] = tn;
            Facc[mi] += cf.cF[j] * tn;
            Qacc[mi] += cf.cQ[j] * tn;
            ushort4 hv, lv;
            hv.x = bf16_rne(tn[0]); lv.x = bf16_rne(tn[0] - bf16_to_f(hv.x));
            hv.y = bf16_rne(tn[1]); lv.y = bf16_rne(tn[1] - bf16_to_f(hv.y));
            hv.z = bf16_rne(tn[2]); lv.z = bf16_rne(tn[2] - bf16_to_f(hv.z));
            hv.w = bf16_rne(tn[3]); lv.w = bf16_rne(tn[3] - bf16_to_f(hv.w));
            *(ushort4*)&dH[c * WP + mi * 16 + q * 4] = hv;
            *(ushort4*)&dL[c * WP + mi * 16 + q * 4] = lv;
        }
    }

    // F slab in the buffer half not holding T_{D_CH} (D_CH even -> slabs 0..3)
    unsigned short* fH = &sTH[(4 + wid) * 16 * WP];
    unsigned short* fL = &sTL[(4 + wid) * 16 * WP];
#pragma unroll
    for (int mi = 0; mi < 4; ++mi) {
        ushort4 hv, lv;
        hv.x = bf16_rne(Facc[mi][0]); lv.x = bf16_rne(Facc[mi][0] - bf16_to_f(hv.x));
        hv.y = bf16_rne(Facc[mi][1]); lv.y = bf16_rne(Facc[mi][1] - bf16_to_f(hv.y));
        hv.z = bf16_rne(Facc[mi][2]); lv.z = bf16_rne(Facc[mi][2] - bf16_to_f(hv.z));
        hv.w = bf16_rne(Facc[mi][3]); lv.w = bf16_rne(Facc[mi][3] - bf16_to_f(hv.w));
        *(ushort4*)&fH[c * WP + mi * 16 + q * 4] = hv;
        *(ushort4*)&fL[c * WP + mi * 16 + q * 4] = lv;
        *(v4f*)&ws[OFF_Q6 + (size_t)k * 4096 + n_ * 64 + mi * 16 + q * 4] = Qacc[mi];
    }

    {
        float p = 0.f;
        const int eb = q * 16;
        v8s h0 = *(const v8s*)&fH[c * WP + eb];
        v8s h1 = *(const v8s*)&fH[c * WP + eb + 8];
        v8s l0 = *(const v8s*)&fL[c * WP + eb];
        v8s l1 = *(const v8s*)&fL[c * WP + eb + 8];
#pragma unroll
        for (int jj = 0; jj < 8; ++jj) {
            p += (bf16_to_f((unsigned short)h0[jj]) + bf16_to_f((unsigned short)l0[jj])) * sV[eb + jj];
            p += (bf16_to_f((unsigned short)h1[jj]) + bf16_to_f((unsigned short)l1[jj])) * sV[eb + 8 + jj];
        }
        p += __shfl_xor(p, 16, 64);
        p += __shfl_xor(p, 32, 64);
        if (q == 0) ws[OFF_VT + (size_t)k * 64 + n_] = p;
    }

    v8s fbH[2], fbL[2];
#pragma unroll
    for (int kc = 0; kc < 2; ++kc) {
        fbH[kc] = *(const v8s*)&fH[c * WP + kc * 32 + q * 8];
        fbL[kc] = *(const v8s*)&fL[c * WP + kc * 32 + q * 8];
    }
    for (int rc = 0; rc < 4; ++rc) {
        __syncthreads();
#pragma unroll
        for (int i = 0; i < 4; ++i) {
            int lin = t + 256 * i;
            int g = lin >> 4, e4 = lin & 15;
            float4 x = *(const float4*)&w[((size_t)k * G_ + rc * 64 + g) * 64 + e4 * 4];
            ushort4 hv, lv;
            hv.x = bf16_rne(x.x); lv.x = bf16_rne(x.x - bf16_to_f(hv.x));
            hv.y = bf16_rne(x.y); lv.y = bf16_rne(x.y - bf16_to_f(hv.y));
            hv.z = bf16_rne(x.z); lv.z = bf16_rne(x.z - bf16_to_f(hv.z));
            hv.w = bf16_rne(x.w); lv.w = bf16_rne(x.w - bf16_to_f(hv.w));
            *(ushort4*)&sXH[g * WP + e4 * 4] = hv;
            *(ushort4*)&sXL[g * WP + e4 * 4] = lv;
        }
        __syncthreads();
#pragma unroll
        for (int mi = 0; mi < 4; ++mi) {
            v4f acc = (v4f){0.f, 0.f, 0.f, 0.f};
#pragma unroll
            for (int kc = 0; kc < 2; ++kc) {
                v8s aH = *(const v8s*)&sXH[(mi * 16 + c) * WP + kc * 32 + q * 8];
                v8s aL = *(const v8s*)&sXL[(mi * 16 + c) * WP + kc * 32 + q * 8];
                acc = __builtin_amdgcn_mfma_f32_16x16x32_bf16(aH, fbH[kc], acc, 0, 0, 0);
                acc = __builtin_amdgcn_mfma_f32_16x16x32_bf16(aH, fbL[kc], acc, 0, 0, 0);
                acc = __builtin_amdgcn_mfma_f32_16x16x32_bf16(aL, fbH[kc], acc, 0, 0, 0);
            }
            ushort4 hv, lv;
            hv.x = bf16_rne(acc[0]); lv.x = bf16_rne(acc[0] - bf16_to_f(hv.x));
            hv.y = bf16_rne(acc[1]); lv.y = bf16_rne(acc[1] - bf16_to_f(hv.y));
            hv.z = bf16_rne(acc[2]); lv.z = bf16_rne(acc[2] - bf16_to_f(hv.z));
            hv.w = bf16_rne(acc[3]); lv.w = bf16_rne(acc[3] - bf16_to_f(hv.w));
            size_t goff = ((size_t)k * 80 + n_) * 256 + rc * 64 + mi * 16 + q * 4;
            *(ushort4*)&wtTH[goff] = hv;
            *(ushort4*)&wtTL[goff] = lv;
        }
    }
}

// ---------------------------------------------------------------------------
// G1 v3: grid 2048 1-D, block 256 (4 waves). XCD x (= id&7) owns k in [32x,32x+32).
// img A-frags: direct global->reg issued at TOP of each gc (latency overlapped
// with staging + barrier drain; short-lived regs only -> no spill).
// wt: LDS double-buffered, ONE barrier/gc (write buf_i; sync; read buf_i —
// next write of buf_i is two syncs later). Scores: transposed SCt[k][b].
__global__ __launch_bounds__(256) void g1_kernel(float* __restrict__ ws) {
    const int L = blockIdx.x;
    const int xcdk = L & 7;
    const int rr = L >> 3;
    const int btile = rr & 7;
    const int klow = rr >> 3;
    const int k = xcdk * 32 + klow;
    const int b0 = btile * 128;
    const int t = threadIdx.x;
    const int wid = t >> 6, lane = t & 63;
    const int c = lane & 15, q = lane >> 4;
    __shared__ __align__(16) unsigned short sWH[2][80 * LP];
    __shared__ __align__(16) unsigned short sWL[2][80 * LP];
    __shared__ float sSC[128];

    const unsigned short* wsu = (const unsigned short*)(ws + OFF_U16);
    const unsigned short* wtTH = wsu + U_WTH;
    const unsigned short* wtTL = wsu + U_WTL;
    const unsigned short* imgH = wsu + U_IMGH;
    const unsigned short* imgL = wsu + U_IMGL;

    v4f acc[2][5];
#pragma unroll
    for (int mt = 0; mt < 2; ++mt)
#pragma unroll
        for (int nt = 0; nt < 5; ++nt) acc[mt][nt] = (v4f){0.f, 0.f, 0.f, 0.f};

    for (int gc = 0; gc < 8; ++gc) {
        const int buf = gc & 1;
        // --- issue ALL global loads for this gc first (latency overlap) ---
        v8s aH[2], aL[2];
#pragma unroll
        for (int mt = 0; mt < 2; ++mt) {
            size_t off = (size_t)(b0 + wid * 32 + mt * 16 + c) * 256 + gc * 32 + q * 8;
            aH[mt] = *(const v8s*)&imgH[off];
            aL[mt] = *(const v8s*)&imgL[off];
        }
        uint4 wv[3];
        int v0 = 0, v1 = 0, v2 = 0;
        {
#pragma unroll
            for (int r = 0; r < 3; ++r) {
                int idx = t + 256 * r;
                if (idx < 640) {
                    int pl = idx >= 320 ? 1 : 0;
                    int j = idx - pl * 320;
                    int col = j >> 2, seg = j & 3;
                    const unsigned short* src = pl ? wtTL : wtTH;
                    wv[r] = *(const uint4*)&src[((size_t)k * 80 + col) * 256 + gc * 32 + seg * 8];
                    if (r == 0) v0 = 1; else if (r == 1) v1 = 1; else v2 = 1;
                }
            }
        }
        // --- commit wt to LDS buf ---
#pragma unroll
        for (int r = 0; r < 3; ++r) {
            int idx = t + 256 * r;
            int ok = (r == 0) ? v0 : (r == 1) ? v1 : v2;
            if (ok) {
                int pl = idx >= 320 ? 1 : 0;
                int j = idx - pl * 320;
                int col = j >> 2, seg = j & 3;
                unsigned short* dst = pl ? sWL[buf] : sWH[buf];
                *(uint4*)&dst[col * LP + seg * 8] = wv[r];
            }
        }
        __syncthreads();
        // --- MFMAs ---
#pragma unroll
        for (int nt = 0; nt < 5; ++nt) {
            int colr = nt * 16 + c;
            v8s bH = *(const v8s*)&sWH[buf][colr * LP + q * 8];
            v8s bL = *(const v8s*)&sWL[buf][colr * LP + q * 8];
#pragma unroll
            for (int mt = 0; mt < 2; ++mt) {
                acc[mt][nt] = __builtin_amdgcn_mfma_f32_16x16x32_bf16(aH[mt], bH, acc[mt][nt], 0, 0, 0);
                acc[mt][nt] = __builtin_amdgcn_mfma_f32_16x16x32_bf16(aH[mt], bL, acc[mt][nt], 0, 0, 0);
                acc[mt][nt] = __builtin_amdgcn_mfma_f32_16x16x32_bf16(aL[mt], bH, acc[mt][nt], 0, 0, 0);
            }
        }
    }
    // epilogue: C layout col=lane&15, row=q*4+r; block-owned transposed store.
    float msq = ws[OFF_MSQ + k];
    float vtr[4];
#pragma unroll
    for (int nt = 0; nt < 4; ++nt)
        vtr[nt] = ws[OFF_VT + (size_t)k * 64 + nt * 16 + c];
#pragma unroll
    for (int mt = 0; mt < 2; ++mt) {
        float tot[4];
#pragma unroll
        for (int r = 0; r < 4; ++r) tot[r] = 0.f;
#pragma unroll
        for (int nt = 0; nt < 4; ++nt)
#pragma unroll
            for (int r = 0; r < 4; ++r) {
                float d = acc[mt][nt][r] - vtr[nt];
                tot[r] += d * d;
            }
        if (c == 0) {
#pragma unroll
            for (int r = 0; r < 4; ++r) tot[r] += 2.f * acc[mt][4][r];
        }
#pragma unroll
        for (int r = 0; r < 4; ++r) {
            tot[r] += __shfl_xor(tot[r], 1, 64);
            tot[r] += __shfl_xor(tot[r], 2, 64);
            tot[r] += __shfl_xor(tot[r], 4, 64);
            tot[r] += __shfl_xor(tot[r], 8, 64);
        }
        if (c == 0) {
#pragma unroll
            for (int r = 0; r < 4; ++r)
                sSC[wid * 32 + mt * 16 + q * 4 + r] = msq - tot[r];
        }
    }
    __syncthreads();
    if (t < 32) {
        float4 v = *(const float4*)&sSC[t * 4];
        *(float4*)&ws[OFF_SC + (size_t)k * B_ + b0 + t * 4] = v;
    }
}

// ---------------------------------------------------------------------------
// G2: per b: argmin_k of SCt[k][b] (first-index tie-break), then
//     u = W_k^T img - v ; z6 = Q6 u ; y = W_k z6 + m_k    (grid B, block 256)
__global__ __launch_bounds__(256) void g2_kernel(const float* __restrict__ img,
                                                 const float* __restrict__ mu,
                                                 const float* __restrict__ w,
                                                 const float* __restrict__ ws,
                                                 float* __restrict__ out) {
    const int b = blockIdx.x;
    const int t = threadIdx.x;
    __shared__ float rv[4];
    __shared__ int ri[4];
    __shared__ int skbest;
    __shared__ float simg[256];
    __shared__ float up[4][64];
    __shared__ float su[64];
    __shared__ float sz[64];

    float val = ws[OFF_SC + (size_t)t * B_ + b];   // transposed read
    int idx = t;
#pragma unroll
    for (int off = 32; off >= 1; off >>= 1) {
        float ov = __shfl_down(val, off, 64);
        int oi = __shfl_down(idx, off, 64);
        if (ov < val || (ov == val && oi < idx)) { val = ov; idx = oi; }
    }
    if ((t & 63) == 0) { rv[t >> 6] = val; ri[t >> 6] = idx; }
    simg[t] = img[(size_t)b * G_ + t];
    __syncthreads();
    if (t == 0) {
        float bv = rv[0]; int bi = ri[0];
#pragma unroll
        for (int i = 1; i < 4; ++i)
            if (rv[i] < bv || (rv[i] == bv && ri[i] < bi)) { bv = rv[i]; bi = ri[i]; }
        skbest = bi;
    }
    __syncthreads();
    const int kb = skbest;
    const int e = t & 63, p = t >> 6;

    {
        float acc = 0.f;
        const float* wcol = w + ((size_t)kb * G_ + p * 64) * E_ + e;
        for (int g = 0; g < 64; ++g) acc += wcol[(size_t)g * E_] * simg[p * 64 + g];
        up[p][e] = acc;
    }
    __syncthreads();
    if (t < 64)
        su[t] = up[0][t] + up[1][t] + up[2][t] + up[3][t] - ws[OFF_V + (size_t)kb * 64 + t];
    __syncthreads();
    {
        float acc = 0.f;
        const float* qrow = ws + OFF_Q6 + (size_t)kb * 4096 + e * 64 + p * 16;
#pragma unroll
        for (int f = 0; f < 16; ++f) acc += qrow[f] * su[p * 16 + f];
        up[p][e] = acc;
    }
    __syncthreads();
    if (t < 64) sz[t] = up[0][t] + up[1][t] + up[2][t] + up[3][t];
    __syncthreads();
    {
        float acc = 0.f;
        const float* wrow = w + ((size_t)kb * G_ + t) * E_;
#pragma unroll 8
        for (int e2 = 0; e2 < 64; ++e2) acc += wrow[e2] * sz[e2];
        out[(size_t)b * G_ + t] = acc + mu[(size_t)t * K_ + kb];
    }
}

// ---------------------------------------------------------------------------
extern "C" void kernel_launch(void* const* d_in, const int* in_sizes, int n_in,
                              void* d_out, int out_size, void* d_ws, size_t ws_size,
                              hipStream_t stream) {
    const float* img = (const float*)d_in[0];
    const float* mu  = (const float*)d_in[1];
    const float* w   = (const float*)d_in[2];
    float* out = (float*)d_out;
    float* ws = (float*)d_ws;

    const double aa = 0.06, bb = 1.85;
    const int NN = 64;
    double fF[NN], fQ[NN];
    for (int i = 0; i < NN; ++i) {
        double x = cos(M_PI * (i + 0.5) / NN);
        double lam = 0.5 * (aa + bb) + 0.5 * (bb - aa) * x;
        double m = 0.95 - 0.05 * lam;
        double p5 = 0.0, pw = 1.0;
        for (int j = 0; j < 5; ++j) { p5 += pw; pw *= m; }
        double p6 = p5 + pw;
        double p = 2.0 * 0.05 * p5 - 0.05 * 0.05 * lam * p5 * p5;
        fF[i] = sqrt(p);
        fQ[i] = 0.05 * p6;
    }
    Cheb cf;
    for (int j = 0; j <= D_CH; ++j) {
        double sF = 0.0, sQ = 0.0;
        for (int i = 0; i < NN; ++i) {
            double cw = cos(M_PI * j * (i + 0.5) / NN);
            sF += fF[i] * cw;
            sQ += fQ[i] * cw;
        }
        double sc = 2.0 / NN;
        if (j == 0) sc *= 0.5;
        cf.cF[j] = (float)(sF * sc);
        cf.cQ[j] = (float)(sQ * sc);
    }
    cf.alpha = (float)(2.0 / (bb - aa));
    cf.gamma = (float)(-(bb + aa) / (bb - aa));

    hipLaunchKernelGGL(pre_kernel, dim3(K_), dim3(256), 0, stream, img, w, mu, ws, cf);
    hipLaunchKernelGGL(g1_kernel, dim3(2048), dim3(256), 0, stream, ws);
    hipLaunchKernelGGL(g2_kernel, dim3(B_), dim3(256), 0, stream, img, mu, w, ws, out);
}

// Round 13
// 151.799 us; speedup vs baseline: 1.2350x; 1.2350x over previous
//
#include <hip/hip_runtime.h>
#include <math.h>

#define B_ 1024
#define G_ 256
#define K_ 256
#define E_ 64
#define D_CH 8    // Chebyshev degree (branch point ~lambda=-5 -> ~13^-j decay)
#define LP 40     // g1 LDS pitch (ushorts) for 32-g chunks
#define WP 72     // pre LDS pitch (ushorts)

// ws layout (floats)
#define OFF_Q6  ((size_t)0)                          // K*E*E = 1048576
#define OFF_V   ((size_t)1048576)                    // K*E
#define OFF_VT  ((size_t)1064960)                    // K*E
#define OFF_MSQ ((size_t)1081344)                    // K
#define OFF_SC  ((size_t)1081600)                    // K*B (TRANSPOSED: [k][b])
#define OFF_U16 ((size_t)1343744)                    // ushort area (16B aligned)
#define U_WTH  ((size_t)0)           // K*80*256
#define U_WTL  ((size_t)5242880)
#define U_IMGH ((size_t)10485760)    // B*G
#define U_IMGL ((size_t)10747904)

typedef short v8s __attribute__((ext_vector_type(8)));
typedef float v4f __attribute__((ext_vector_type(4)));

struct Cheb { float cF[D_CH + 1]; float cQ[D_CH + 1]; float alpha; float gamma; };

__device__ __forceinline__ unsigned short bf16_rne(float x) {
    unsigned int u = __float_as_uint(x);
    unsigned int r = (u + 0x7FFFu + ((u >> 16) & 1u)) >> 16;
    return (unsigned short)r;
}
__device__ __forceinline__ float bf16_to_f(unsigned short h) {
    return __uint_as_float(((unsigned int)h) << 16);
}

// ---------------------------------------------------------------------------
// pre (MFMA): grid K, block 256 (4 waves). Wave w owns column slab [w*16,w*16+16).
// Barrier-free Chebyshev recurrence. Fused img hi/lo split. Packed phase-A
// staging (column loads + b128 LDS writes). [round-12 version, kept]
__global__ __launch_bounds__(256, 1) void pre_kernel(const float* __restrict__ img,
                                                     const float* __restrict__ w,
                                                     const float* __restrict__ mu,
                                                     float* __restrict__ ws, Cheb cf) {
    const int k = blockIdx.x;
    const int t = threadIdx.x;
    const int wid = t >> 6;
    const int lane = t & 63;
    const int c = lane & 15, q = lane >> 4;
    const int n_ = wid * 16 + c;

    __shared__ __align__(16) unsigned short sXH[64 * WP];
    __shared__ __align__(16) unsigned short sXL[64 * WP];
    __shared__ __align__(16) unsigned short sTH[8 * 16 * WP];
    __shared__ __align__(16) unsigned short sTL[8 * 16 * WP];
    __shared__ float sMu[64];
    __shared__ float sV[64];
    __shared__ float dred[256];

    unsigned short* wsu = (unsigned short*)(ws + OFF_U16);
    unsigned short* wtTH = wsu + U_WTH;
    unsigned short* wtTL = wsu + U_WTL;

    {
        unsigned short* imgH = wsu + U_IMGH;
        unsigned short* imgL = wsu + U_IMGL;
        int i = k * 256 + t;
        float4 x = ((const float4*)img)[i];
        ushort4 h, l;
        h.x = bf16_rne(x.x); l.x = bf16_rne(x.x - bf16_to_f(h.x));
        h.y = bf16_rne(x.y); l.y = bf16_rne(x.y - bf16_to_f(h.y));
        h.z = bf16_rne(x.z); l.z = bf16_rne(x.z - bf16_to_f(h.z));
        h.w = bf16_rne(x.w); l.w = bf16_rne(x.w - bf16_to_f(h.w));
        ((ushort4*)imgH)[i] = h;
        ((ushort4*)imgL)[i] = l;
    }

    v4f accA[4];
#pragma unroll
    for (int mi = 0; mi < 4; ++mi) accA[mi] = (v4f){0.f, 0.f, 0.f, 0.f};
    float vacc = 0.f, msqacc = 0.f;

    for (int gc = 0; gc < 4; ++gc) {
        __syncthreads();
        {
            const int e = t & 63;
            const int g0 = (t >> 6) * 16;
            unsigned int hp[8], lp[8];
#pragma unroll
            for (int j = 0; j < 8; ++j) {
                float x0 = w[((size_t)k * G_ + gc * 64 + g0 + 2 * j) * 64 + e];
                float x1 = w[((size_t)k * G_ + gc * 64 + g0 + 2 * j + 1) * 64 + e];
                unsigned short h0 = bf16_rne(x0);
                unsigned short l0 = bf16_rne(x0 - bf16_to_f(h0));
                unsigned short h1 = bf16_rne(x1);
                unsigned short l1 = bf16_rne(x1 - bf16_to_f(h1));
                hp[j] = (unsigned int)h0 | ((unsigned int)h1 << 16);
                lp[j] = (unsigned int)l0 | ((unsigned int)l1 << 16);
            }
            uint4 u0 = make_uint4(hp[0], hp[1], hp[2], hp[3]);
            uint4 u1 = make_uint4(hp[4], hp[5], hp[6], hp[7]);
            uint4 v0 = make_uint4(lp[0], lp[1], lp[2], lp[3]);
            uint4 v1 = make_uint4(lp[4], lp[5], lp[6], lp[7]);
            *(uint4*)&sTH[e * WP + g0] = u0;
            *(uint4*)&sTH[e * WP + g0 + 8] = u1;
            *(uint4*)&sTL[e * WP + g0] = v0;
            *(uint4*)&sTL[e * WP + g0 + 8] = v1;
        }
        if (t < 64) {
            float m = mu[(size_t)(gc * 64 + t) * K_ + k];
            sMu[t] = m;
            unsigned short h = bf16_rne(m);
            unsigned short l = bf16_rne(m - bf16_to_f(h));
            size_t gcol = ((size_t)k * 80 + 64) * 256 + gc * 64 + t;
            wtTH[gcol] = h;
            wtTL[gcol] = l;
        }
        __syncthreads();
#pragma unroll
        for (int kc = 0; kc < 2; ++kc) {
            v8s bH = *(const v8s*)&sTH[(wid * 16 + c) * WP + kc * 32 + q * 8];
            v8s bL = *(const v8s*)&sTL[(wid * 16 + c) * WP + kc * 32 + q * 8];
#pragma unroll
            for (int mi = 0; mi < 4; ++mi) {
                v8s aH = *(const v8s*)&sTH[(mi * 16 + c) * WP + kc * 32 + q * 8];
                v8s aL = *(const v8s*)&sTL[(mi * 16 + c) * WP + kc * 32 + q * 8];
                accA[mi] = __builtin_amdgcn_mfma_f32_16x16x32_bf16(aH, bH, accA[mi], 0, 0, 0);
                accA[mi] = __builtin_amdgcn_mfma_f32_16x16x32_bf16(aH, bL, accA[mi], 0, 0, 0);
                accA[mi] = __builtin_amdgcn_mfma_f32_16x16x32_bf16(aL, bH, accA[mi], 0, 0, 0);
            }
        }
        for (int gg = wid * 16; gg < wid * 16 + 16; ++gg) {
            float rec = bf16_to_f(sTH[lane * WP + gg]) + bf16_to_f(sTL[lane * WP + gg]);
            vacc += rec * sMu[gg];
        }
        if (t == 255) {
            for (int gg = 0; gg < 64; ++gg) msqacc += sMu[gg] * sMu[gg];
        }
    }
    dred[t] = vacc;
    if (t == 255) ws[OFF_MSQ + k] = msqacc;
    __syncthreads();
    if (t < 64) {
        float v = dred[t] + dred[t + 64] + dred[t + 128] + dred[t + 192];
        sV[t] = v;
        ws[OFF_V + (size_t)k * 64 + t] = v;
    }

    v4f Tcur[4], Told[4], Facc[4], Qacc[4];
#pragma unroll
    for (int mi = 0; mi < 4; ++mi) {
        ushort4 hv, lv;
        float xr[4];
#pragma unroll
        for (int r = 0; r < 4; ++r) {
            int m = mi * 16 + q * 4 + r;
            float id = (m == n_) ? 1.f : 0.f;
            float xv = cf.alpha * accA[mi][r] + cf.gamma * id;
            xr[r] = xv;
            Tcur[mi][r] = xv;
            Told[mi][r] = id;
            Facc[mi][r] = cf.cF[0] * id + cf.cF[1] * xv;
            Qacc[mi][r] = cf.cQ[0] * id + cf.cQ[1] * xv;
        }
        hv.x = bf16_rne(xr[0]); lv.x = bf16_rne(xr[0] - bf16_to_f(hv.x));
        hv.y = bf16_rne(xr[1]); lv.y = bf16_rne(xr[1] - bf16_to_f(hv.y));
        hv.z = bf16_rne(xr[2]); lv.z = bf16_rne(xr[2] - bf16_to_f(hv.z));
        hv.w = bf16_rne(xr[3]); lv.w = bf16_rne(xr[3] - bf16_to_f(hv.w));
        *(ushort4*)&sXH[n_ * WP + mi * 16 + q * 4] = hv;
        *(ushort4*)&sXL[n_ * WP + mi * 16 + q * 4] = lv;
    }
    __syncthreads();
    v8s xaH[4][2], xaL[4][2];
#pragma unroll
    for (int mi = 0; mi < 4; ++mi)
#pragma unroll
        for (int kc = 0; kc < 2; ++kc) {
            xaH[mi][kc] = *(const v8s*)&sXH[(mi * 16 + c) * WP + kc * 32 + q * 8];
            xaL[mi][kc] = *(const v8s*)&sXL[(mi * 16 + c) * WP + kc * 32 + q * 8];
        }

#pragma unroll
    for (int j = 2; j <= D_CH; ++j) {
        const unsigned short* sH =
            (j == 2) ? &sXH[(wid * 16) * WP] : &sTH[((((j - 1) & 1)) * 4 + wid) * 16 * WP];
        const unsigned short* sL =
            (j == 2) ? &sXL[(wid * 16) * WP] : &sTL[((((j - 1) & 1)) * 4 + wid) * 16 * WP];
        unsigned short* dH = &sTH[((j & 1) * 4 + wid) * 16 * WP];
        unsigned short* dL = &sTL[((j & 1) * 4 + wid) * 16 * WP];
        v8s tbH[2], tbL[2];
#pragma unroll
        for (int kc = 0; kc < 2; ++kc) {
            tbH[kc] = *(const v8s*)&sH[c * WP + kc * 32 + q * 8];
            tbL[kc] = *(const v8s*)&sL[c * WP + kc * 32 + q * 8];
        }
#pragma unroll
        for (int mi = 0; mi < 4; ++mi) {
            v4f gt = (v4f){0.f, 0.f, 0.f, 0.f};
#pragma unroll
            for (int kc = 0; kc < 2; ++kc) {
                gt = __builtin_amdgcn_mfma_f32_16x16x32_bf16(xaH[mi][kc], tbH[kc], gt, 0, 0, 0);
                gt = __builtin_amdgcn_mfma_f32_16x16x32_bf16(xaH[mi][kc], tbL[kc], gt, 0, 0, 0);
                gt = __builtin_amdgcn_mfma_f32_16x16x32_bf16(xaL[mi][kc], tbH[kc], gt, 0, 0, 0);
            }
            v4f tn = 2.f * gt - Told[mi];
            Told[mi] = Tcur[mi];
            Tcur[mi] = tn;
            Facc[mi] += cf.cF[j] * tn;
            Qacc[mi] += cf.cQ[j] * tn;
            ushort4 hv, lv;
            hv.x = bf16_rne(tn[0]); lv.x = bf16_rne(tn[0] - bf16_to_f(hv.x));
            hv.y = bf16_rne(tn[1]); lv.y = bf16_rne(tn[1] - bf16_to_f(hv.y));
            hv.z = bf16_rne(tn[2]); lv.z = bf16_rne(tn[2] - bf16_to_f(hv.z));
            hv.w = bf16_rne(tn[3]); lv.w = bf16_rne(tn[3] - bf16_to_f(hv.w));
            *(ushort4*)&dH[c * WP + mi * 16 + q * 4] = hv;
            *(ushort4*)&dL[c * WP + mi * 16 + q * 4] = lv;
        }
    }

    unsigned short* fH = &sTH[(4 + wid) * 16 * WP];
    unsigned short* fL = &sTL[(4 + wid) * 16 * WP];
#pragma unroll
    for (int mi = 0; mi < 4; ++mi) {
        ushort4 hv, lv;
        hv.x = bf16_rne(Facc[mi][0]); lv.x = bf16_rne(Facc[mi][0] - bf16_to_f(hv.x));
        hv.y = bf16_rne(Facc[mi][1]); lv.y = bf16_rne(Facc[mi][1] - bf16_to_f(hv.y));
        hv.z = bf16_rne(Facc[mi][2]); lv.z = bf16_rne(Facc[mi][2] - bf16_to_f(hv.z));
        hv.w = bf16_rne(Facc[mi][3]); lv.w = bf16_rne(Facc[mi][3] - bf16_to_f(hv.w));
        *(ushort4*)&fH[c * WP + mi * 16 + q * 4] = hv;
        *(ushort4*)&fL[c * WP + mi * 16 + q * 4] = lv;
        *(v4f*)&ws[OFF_Q6 + (size_t)k * 4096 + n_ * 64 + mi * 16 + q * 4] = Qacc[mi];
    }

    {
        float p = 0.f;
        const int eb = q * 16;
        v8s h0 = *(const v8s*)&fH[c * WP + eb];
        v8s h1 = *(const v8s*)&fH[c * WP + eb + 8];
        v8s l0 = *(const v8s*)&fL[c * WP + eb];
        v8s l1 = *(const v8s*)&fL[c * WP + eb + 8];
#pragma unroll
        for (int jj = 0; jj < 8; ++jj) {
            p += (bf16_to_f((unsigned short)h0[jj]) + bf16_to_f((unsigned short)l0[jj])) * sV[eb + jj];
            p += (bf16_to_f((unsigned short)h1[jj]) + bf16_to_f((unsigned short)l1[jj])) * sV[eb + 8 + jj];
        }
        p += __shfl_xor(p, 16, 64);
        p += __shfl_xor(p, 32, 64);
        if (q == 0) ws[OFF_VT + (size_t)k * 64 + n_] = p;
    }

    v8s fbH[2], fbL[2];
#pragma unroll
    for (int kc = 0; kc < 2; ++kc) {
        fbH[kc] = *(const v8s*)&fH[c * WP + kc * 32 + q * 8];
        fbL[kc] = *(const v8s*)&fL[c * WP + kc * 32 + q * 8];
    }
    for (int rc = 0; rc < 4; ++rc) {
        __syncthreads();
#pragma unroll
        for (int i = 0; i < 4; ++i) {
            int lin = t + 256 * i;
            int g = lin >> 4, e4 = lin & 15;
            float4 x = *(const float4*)&w[((size_t)k * G_ + rc * 64 + g) * 64 + e4 * 4];
            ushort4 hv, lv;
            hv.x = bf16_rne(x.x); lv.x = bf16_rne(x.x - bf16_to_f(hv.x));
            hv.y = bf16_rne(x.y); lv.y = bf16_rne(x.y - bf16_to_f(hv.y));
            hv.z = bf16_rne(x.z); lv.z = bf16_rne(x.z - bf16_to_f(hv.z));
            hv.w = bf16_rne(x.w); lv.w = bf16_rne(x.w - bf16_to_f(hv.w));
            *(ushort4*)&sXH[g * WP + e4 * 4] = hv;
            *(ushort4*)&sXL[g * WP + e4 * 4] = lv;
        }
        __syncthreads();
#pragma unroll
        for (int mi = 0; mi < 4; ++mi) {
            v4f acc = (v4f){0.f, 0.f, 0.f, 0.f};
#pragma unroll
            for (int kc = 0; kc < 2; ++kc) {
                v8s aH = *(const v8s*)&sXH[(mi * 16 + c) * WP + kc * 32 + q * 8];
                v8s aL = *(const v8s*)&sXL[(mi * 16 + c) * WP + kc * 32 + q * 8];
                acc = __builtin_amdgcn_mfma_f32_16x16x32_bf16(aH, fbH[kc], acc, 0, 0, 0);
                acc = __builtin_amdgcn_mfma_f32_16x16x32_bf16(aH, fbL[kc], acc, 0, 0, 0);
                acc = __builtin_amdgcn_mfma_f32_16x16x32_bf16(aL, fbH[kc], acc, 0, 0, 0);
            }
            ushort4 hv, lv;
            hv.x = bf16_rne(acc[0]); lv.x = bf16_rne(acc[0] - bf16_to_f(hv.x));
            hv.y = bf16_rne(acc[1]); lv.y = bf16_rne(acc[1] - bf16_to_f(hv.y));
            hv.z = bf16_rne(acc[2]); lv.z = bf16_rne(acc[2] - bf16_to_f(hv.z));
            hv.w = bf16_rne(acc[3]); lv.w = bf16_rne(acc[3] - bf16_to_f(hv.w));
            size_t goff = ((size_t)k * 80 + n_) * 256 + rc * 64 + mi * 16 + q * 4;
            *(ushort4*)&wtTH[goff] = hv;
            *(ushort4*)&wtTL[goff] = lv;
        }
    }
}

// ---------------------------------------------------------------------------
// G1 (round-11 validated, 44.7 us): grid 2048 1-D, block 256 (4 waves).
// XCD x (= id&7) owns k in [32x,32x+32). Both img and wt staged via LDS
// (2 barriers/gc, load->store immediately — the only non-spilling shape).
// Scores stored transposed SCt[k][b], block-owned 64B lines.
__global__ __launch_bounds__(256) void g1_kernel(float* __restrict__ ws) {
    const int L = blockIdx.x;
    const int xcdk = L & 7;
    const int rr = L >> 3;
    const int btile = rr & 7;
    const int klow = rr >> 3;
    const int k = xcdk * 32 + klow;
    const int b0 = btile * 128;
    const int t = threadIdx.x;
    const int wid = t >> 6, lane = t & 63;
    const int c = lane & 15, q = lane >> 4;
    __shared__ __align__(16) unsigned short sIH[128 * LP];
    __shared__ __align__(16) unsigned short sIL[128 * LP];
    __shared__ __align__(16) unsigned short sWH[80 * LP];
    __shared__ __align__(16) unsigned short sWL[80 * LP];
    __shared__ float sSC[128];

    const unsigned short* wsu = (const unsigned short*)(ws + OFF_U16);
    const unsigned short* wtTH = wsu + U_WTH;
    const unsigned short* wtTL = wsu + U_WTL;
    const unsigned short* imgH = wsu + U_IMGH;
    const unsigned short* imgL = wsu + U_IMGL;

    v4f acc[2][5];
#pragma unroll
    for (int mt = 0; mt < 2; ++mt)
#pragma unroll
        for (int nt = 0; nt < 5; ++nt) acc[mt][nt] = (v4f){0.f, 0.f, 0.f, 0.f};

    for (int gc = 0; gc < 8; ++gc) {
        __syncthreads();
#pragma unroll
        for (int i = 0; i < 2; ++i) {
            int idx = t + 256 * i;
            int r = idx >> 2, seg = idx & 3;
            size_t gsrc = (size_t)(b0 + r) * 256 + gc * 32 + seg * 8;
            *(uint4*)&sIH[r * LP + seg * 8] = *(const uint4*)&imgH[gsrc];
            *(uint4*)&sIL[r * LP + seg * 8] = *(const uint4*)&imgL[gsrc];
        }
        {
            int col = t >> 2, seg = t & 3;
            size_t gsrc = ((size_t)k * 80 + col) * 256 + gc * 32 + seg * 8;
            *(uint4*)&sWH[col * LP + seg * 8] = *(const uint4*)&wtTH[gsrc];
            *(uint4*)&sWL[col * LP + seg * 8] = *(const uint4*)&wtTL[gsrc];
            if (t < 64) {
                int idx = t + 256;
                int col2 = idx >> 2, seg2 = idx & 3;
                size_t g2 = ((size_t)k * 80 + col2) * 256 + gc * 32 + seg2 * 8;
                *(uint4*)&sWH[col2 * LP + seg2 * 8] = *(const uint4*)&wtTH[g2];
                *(uint4*)&sWL[col2 * LP + seg2 * 8] = *(const uint4*)&wtTL[g2];
            }
        }
        __syncthreads();
        v8s aH[2], aL[2];
#pragma unroll
        for (int mt = 0; mt < 2; ++mt) {
            int row = wid * 32 + mt * 16 + c;
            aH[mt] = *(const v8s*)&sIH[row * LP + q * 8];
            aL[mt] = *(const v8s*)&sIL[row * LP + q * 8];
        }
#pragma unroll
        for (int nt = 0; nt < 5; ++nt) {
            int colr = nt * 16 + c;
            v8s bH = *(const v8s*)&sWH[colr * LP + q * 8];
            v8s bL = *(const v8s*)&sWL[colr * LP + q * 8];
#pragma unroll
            for (int mt = 0; mt < 2; ++mt) {
                acc[mt][nt] = __builtin_amdgcn_mfma_f32_16x16x32_bf16(aH[mt], bH, acc[mt][nt], 0, 0, 0);
                acc[mt][nt] = __builtin_amdgcn_mfma_f32_16x16x32_bf16(aH[mt], bL, acc[mt][nt], 0, 0, 0);
                acc[mt][nt] = __builtin_amdgcn_mfma_f32_16x16x32_bf16(aL[mt], bH, acc[mt][nt], 0, 0, 0);
            }
        }
    }
    float msq = ws[OFF_MSQ + k];
    float vtr[4];
#pragma unroll
    for (int nt = 0; nt < 4; ++nt)
        vtr[nt] = ws[OFF_VT + (size_t)k * 64 + nt * 16 + c];
#pragma unroll
    for (int mt = 0; mt < 2; ++mt) {
        float tot[4];
#pragma unroll
        for (int r = 0; r < 4; ++r) tot[r] = 0.f;
#pragma unroll
        for (int nt = 0; nt < 4; ++nt)
#pragma unroll
            for (int r = 0; r < 4; ++r) {
                float d = acc[mt][nt][r] - vtr[nt];
                tot[r] += d * d;
            }
        if (c == 0) {
#pragma unroll
            for (int r = 0; r < 4; ++r) tot[r] += 2.f * acc[mt][4][r];
        }
#pragma unroll
        for (int r = 0; r < 4; ++r) {
            tot[r] += __shfl_xor(tot[r], 1, 64);
            tot[r] += __shfl_xor(tot[r], 2, 64);
            tot[r] += __shfl_xor(tot[r], 4, 64);
            tot[r] += __shfl_xor(tot[r], 8, 64);
        }
        if (c == 0) {
#pragma unroll
            for (int r = 0; r < 4; ++r)
                sSC[wid * 32 + mt * 16 + q * 4 + r] = msq - tot[r];
        }
    }
    __syncthreads();
    if (t < 32) {
        float4 v = *(const float4*)&sSC[t * 4];
        *(float4*)&ws[OFF_SC + (size_t)k * B_ + b0 + t * 4] = v;
    }
}

// ---------------------------------------------------------------------------
// G2: per b: argmin_k of SCt[k][b], then u = W_k^T img - v ; z6 = Q6 u ;
// y = W_k z6 + m_k. Decode retiled: 16-lane row groups read W rows as
// coalesced float4; mu_k from the coalesced bf16 hi/lo column in wtT.
__global__ __launch_bounds__(256) void g2_kernel(const float* __restrict__ img,
                                                 const float* __restrict__ w,
                                                 const float* __restrict__ ws,
                                                 float* __restrict__ out) {
    const int b = blockIdx.x;
    const int t = threadIdx.x;
    const int wid = t >> 6, lane = t & 63;
    __shared__ float rv[4];
    __shared__ int ri[4];
    __shared__ int skbest;
    __shared__ float simg[256];
    __shared__ float up[4][64];
    __shared__ float su[64];
    __shared__ __align__(16) float sz[64];
    __shared__ float yrow[256];

    const unsigned short* wsu = (const unsigned short*)(ws + OFF_U16);
    const unsigned short* wtTH = wsu + U_WTH;
    const unsigned short* wtTL = wsu + U_WTL;

    float val = ws[OFF_SC + (size_t)t * B_ + b];   // transposed read
    int idx = t;
#pragma unroll
    for (int off = 32; off >= 1; off >>= 1) {
        float ov = __shfl_down(val, off, 64);
        int oi = __shfl_down(idx, off, 64);
        if (ov < val || (ov == val && oi < idx)) { val = ov; idx = oi; }
    }
    if ((t & 63) == 0) { rv[t >> 6] = val; ri[t >> 6] = idx; }
    simg[t] = img[(size_t)b * G_ + t];
    __syncthreads();
    if (t == 0) {
        float bv = rv[0]; int bi = ri[0];
#pragma unroll
        for (int i = 1; i < 4; ++i)
            if (rv[i] < bv || (rv[i] == bv && ri[i] < bi)) { bv = rv[i]; bi = ri[i]; }
        skbest = bi;
    }
    __syncthreads();
    const int kb = skbest;
    const int e = t & 63, p = t >> 6;

    // u partials (coalesced column reads)
    {
        float acc = 0.f;
        const float* wcol = w + ((size_t)kb * G_ + p * 64) * E_ + e;
        for (int g = 0; g < 64; ++g) acc += wcol[(size_t)g * E_] * simg[p * 64 + g];
        up[p][e] = acc;
    }
    __syncthreads();
    if (t < 64)
        su[t] = up[0][t] + up[1][t] + up[2][t] + up[3][t] - ws[OFF_V + (size_t)kb * 64 + t];
    __syncthreads();
    // z6 partials
    {
        float acc = 0.f;
        const float* qrow = ws + OFF_Q6 + (size_t)kb * 4096 + e * 64 + p * 16;
#pragma unroll
        for (int f = 0; f < 16; ++f) acc += qrow[f] * su[p * 16 + f];
        up[p][e] = acc;
    }
    __syncthreads();
    if (t < 64) sz[t] = up[0][t] + up[1][t] + up[2][t] + up[3][t];
    __syncthreads();
    // decode: wave wid handles rows [wid*64, wid*64+64); 16-lane groups per row
    {
        const int j = lane & 15, rquad = lane >> 4;
        float4 zv = *(const float4*)&sz[j * 4];
#pragma unroll
        for (int sub = 0; sub < 16; ++sub) {
            int row = wid * 64 + sub * 4 + rquad;
            float4 wv = *(const float4*)&w[((size_t)kb * G_ + row) * 64 + j * 4];
            float p2 = wv.x * zv.x + wv.y * zv.y + wv.z * zv.z + wv.w * zv.w;
            p2 += __shfl_xor(p2, 1, 64);
            p2 += __shfl_xor(p2, 2, 64);
            p2 += __shfl_xor(p2, 4, 64);
            p2 += __shfl_xor(p2, 8, 64);
            if (j == 0) yrow[row] = p2;
        }
    }
    __syncthreads();
    {
        size_t mcol = ((size_t)kb * 80 + 64) * 256 + t;
        float m = bf16_to_f(wtTH[mcol]) + bf16_to_f(wtTL[mcol]);
        out[(size_t)b * G_ + t] = yrow[t] + m;
    }
}

// ---------------------------------------------------------------------------
extern "C" void kernel_launch(void* const* d_in, const int* in_sizes, int n_in,
                              void* d_out, int out_size, void* d_ws, size_t ws_size,
                              hipStream_t stream) {
    const float* img = (const float*)d_in[0];
    const float* mu  = (const float*)d_in[1];
    const float* w   = (const float*)d_in[2];
    float* out = (float*)d_out;
    float* ws = (float*)d_ws;

    const double aa = 0.06, bb = 1.85;
    const int NN = 64;
    double fF[NN], fQ[NN];
    for (int i = 0; i < NN; ++i) {
        double x = cos(M_PI * (i + 0.5) / NN);
        double lam = 0.5 * (aa + bb) + 0.5 * (bb - aa) * x;
        double m = 0.95 - 0.05 * lam;
        double p5 = 0.0, pw = 1.0;
        for (int j = 0; j < 5; ++j) { p5 += pw; pw *= m; }
        double p6 = p5 + pw;
        double p = 2.0 * 0.05 * p5 - 0.05 * 0.05 * lam * p5 * p5;
        fF[i] = sqrt(p);
        fQ[i] = 0.05 * p6;
    }
    Cheb cf;
    for (int j = 0; j <= D_CH; ++j) {
        double sF = 0.0, sQ = 0.0;
        for (int i = 0; i < NN; ++i) {
            double cw = cos(M_PI * j * (i + 0.5) / NN);
            sF += fF[i] * cw;
            sQ += fQ[i] * cw;
        }
        double sc = 2.0 / NN;
        if (j == 0) sc *= 0.5;
        cf.cF[j] = (float)(sF * sc);
        cf.cQ[j] = (float)(sQ * sc);
    }
    cf.alpha = (float)(2.0 / (bb - aa));
    cf.gamma = (float)(-(bb + aa) / (bb - aa));

    hipLaunchKernelGGL(pre_kernel, dim3(K_), dim3(256), 0, stream, img, w, mu, ws, cf);
    hipLaunchKernelGGL(g1_kernel, dim3(2048), dim3(256), 0, stream, ws);
    hipLaunchKernelGGL(g2_kernel, dim3(B_), dim3(256), 0, stream, img, w, ws, out);
}

// Round 14
// 151.450 us; speedup vs baseline: 1.2379x; 1.0023x over previous
//
#include <hip/hip_runtime.h>
#include <math.h>

#define B_ 1024
#define G_ 256
#define K_ 256
#define E_ 64
#define D_CH 8    // Chebyshev degree (branch point ~lambda=-5 -> ~13^-j decay)
#define LP 40     // g1 LDS pitch (ushorts) for 32-g chunks
#define WP 72     // pre LDS pitch (ushorts)

// ws layout (floats)
#define OFF_Q6  ((size_t)0)                          // K*E*E = 1048576
#define OFF_V   ((size_t)1048576)                    // K*E
#define OFF_VT  ((size_t)1064960)                    // K*E
#define OFF_MSQ ((size_t)1081344)                    // K
#define OFF_SC  ((size_t)1081600)                    // K*B (TRANSPOSED: [k][b])
#define OFF_U16 ((size_t)1343744)                    // ushort area (16B aligned)
#define U_WTH  ((size_t)0)           // K*80*256
#define U_WTL  ((size_t)5242880)
#define U_IMGH ((size_t)10485760)    // B*G
#define U_IMGL ((size_t)10747904)

typedef short v8s __attribute__((ext_vector_type(8)));
typedef float v4f __attribute__((ext_vector_type(4)));

struct Cheb { float cF[D_CH + 1]; float cQ[D_CH + 1]; float alpha; float gamma; };

__device__ __forceinline__ unsigned short bf16_rne(float x) {
    unsigned int u = __float_as_uint(x);
    unsigned int r = (u + 0x7FFFu + ((u >> 16) & 1u)) >> 16;
    return (unsigned short)r;
}
__device__ __forceinline__ float bf16_to_f(unsigned short h) {
    return __uint_as_float(((unsigned int)h) << 16);
}

// ---------------------------------------------------------------------------
// pre (MFMA): grid K, block 256 (4 waves). [round-13 version, unchanged]
__global__ __launch_bounds__(256, 1) void pre_kernel(const float* __restrict__ img,
                                                     const float* __restrict__ w,
                                                     const float* __restrict__ mu,
                                                     float* __restrict__ ws, Cheb cf) {
    const int k = blockIdx.x;
    const int t = threadIdx.x;
    const int wid = t >> 6;
    const int lane = t & 63;
    const int c = lane & 15, q = lane >> 4;
    const int n_ = wid * 16 + c;

    __shared__ __align__(16) unsigned short sXH[64 * WP];
    __shared__ __align__(16) unsigned short sXL[64 * WP];
    __shared__ __align__(16) unsigned short sTH[8 * 16 * WP];
    __shared__ __align__(16) unsigned short sTL[8 * 16 * WP];
    __shared__ float sMu[64];
    __shared__ float sV[64];
    __shared__ float dred[256];

    unsigned short* wsu = (unsigned short*)(ws + OFF_U16);
    unsigned short* wtTH = wsu + U_WTH;
    unsigned short* wtTL = wsu + U_WTL;

    {
        unsigned short* imgH = wsu + U_IMGH;
        unsigned short* imgL = wsu + U_IMGL;
        int i = k * 256 + t;
        float4 x = ((const float4*)img)[i];
        ushort4 h, l;
        h.x = bf16_rne(x.x); l.x = bf16_rne(x.x - bf16_to_f(h.x));
        h.y = bf16_rne(x.y); l.y = bf16_rne(x.y - bf16_to_f(h.y));
        h.z = bf16_rne(x.z); l.z = bf16_rne(x.z - bf16_to_f(h.z));
        h.w = bf16_rne(x.w); l.w = bf16_rne(x.w - bf16_to_f(h.w));
        ((ushort4*)imgH)[i] = h;
        ((ushort4*)imgL)[i] = l;
    }

    v4f accA[4];
#pragma unroll
    for (int mi = 0; mi < 4; ++mi) accA[mi] = (v4f){0.f, 0.f, 0.f, 0.f};
    float vacc = 0.f, msqacc = 0.f;

    for (int gc = 0; gc < 4; ++gc) {
        __syncthreads();
        {
            const int e = t & 63;
            const int g0 = (t >> 6) * 16;
            unsigned int hp[8], lp[8];
#pragma unroll
            for (int j = 0; j < 8; ++j) {
                float x0 = w[((size_t)k * G_ + gc * 64 + g0 + 2 * j) * 64 + e];
                float x1 = w[((size_t)k * G_ + gc * 64 + g0 + 2 * j + 1) * 64 + e];
                unsigned short h0 = bf16_rne(x0);
                unsigned short l0 = bf16_rne(x0 - bf16_to_f(h0));
                unsigned short h1 = bf16_rne(x1);
                unsigned short l1 = bf16_rne(x1 - bf16_to_f(h1));
                hp[j] = (unsigned int)h0 | ((unsigned int)h1 << 16);
                lp[j] = (unsigned int)l0 | ((unsigned int)l1 << 16);
            }
            uint4 u0 = make_uint4(hp[0], hp[1], hp[2], hp[3]);
            uint4 u1 = make_uint4(hp[4], hp[5], hp[6], hp[7]);
            uint4 v0 = make_uint4(lp[0], lp[1], lp[2], lp[3]);
            uint4 v1 = make_uint4(lp[4], lp[5], lp[6], lp[7]);
            *(uint4*)&sTH[e * WP + g0] = u0;
            *(uint4*)&sTH[e * WP + g0 + 8] = u1;
            *(uint4*)&sTL[e * WP + g0] = v0;
            *(uint4*)&sTL[e * WP + g0 + 8] = v1;
        }
        if (t < 64) {
            float m = mu[(size_t)(gc * 64 + t) * K_ + k];
            sMu[t] = m;
            unsigned short h = bf16_rne(m);
            unsigned short l = bf16_rne(m - bf16_to_f(h));
            size_t gcol = ((size_t)k * 80 + 64) * 256 + gc * 64 + t;
            wtTH[gcol] = h;
            wtTL[gcol] = l;
        }
        __syncthreads();
#pragma unroll
        for (int kc = 0; kc < 2; ++kc) {
            v8s bH = *(const v8s*)&sTH[(wid * 16 + c) * WP + kc * 32 + q * 8];
            v8s bL = *(const v8s*)&sTL[(wid * 16 + c) * WP + kc * 32 + q * 8];
#pragma unroll
            for (int mi = 0; mi < 4; ++mi) {
                v8s aH = *(const v8s*)&sTH[(mi * 16 + c) * WP + kc * 32 + q * 8];
                v8s aL = *(const v8s*)&sTL[(mi * 16 + c) * WP + kc * 32 + q * 8];
                accA[mi] = __builtin_amdgcn_mfma_f32_16x16x32_bf16(aH, bH, accA[mi], 0, 0, 0);
                accA[mi] = __builtin_amdgcn_mfma_f32_16x16x32_bf16(aH, bL, accA[mi], 0, 0, 0);
                accA[mi] = __builtin_amdgcn_mfma_f32_16x16x32_bf16(aL, bH, accA[mi], 0, 0, 0);
            }
        }
        for (int gg = wid * 16; gg < wid * 16 + 16; ++gg) {
            float rec = bf16_to_f(sTH[lane * WP + gg]) + bf16_to_f(sTL[lane * WP + gg]);
            vacc += rec * sMu[gg];
        }
        if (t == 255) {
            for (int gg = 0; gg < 64; ++gg) msqacc += sMu[gg] * sMu[gg];
        }
    }
    dred[t] = vacc;
    if (t == 255) ws[OFF_MSQ + k] = msqacc;
    __syncthreads();
    if (t < 64) {
        float v = dred[t] + dred[t + 64] + dred[t + 128] + dred[t + 192];
        sV[t] = v;
        ws[OFF_V + (size_t)k * 64 + t] = v;
    }

    v4f Tcur[4], Told[4], Facc[4], Qacc[4];
#pragma unroll
    for (int mi = 0; mi < 4; ++mi) {
        ushort4 hv, lv;
        float xr[4];
#pragma unroll
        for (int r = 0; r < 4; ++r) {
            int m = mi * 16 + q * 4 + r;
            float id = (m == n_) ? 1.f : 0.f;
            float xv = cf.alpha * accA[mi][r] + cf.gamma * id;
            xr[r] = xv;
            Tcur[mi][r] = xv;
            Told[mi][r] = id;
            Facc[mi][r] = cf.cF[0] * id + cf.cF[1] * xv;
            Qacc[mi][r] = cf.cQ[0] * id + cf.cQ[1] * xv;
        }
        hv.x = bf16_rne(xr[0]); lv.x = bf16_rne(xr[0] - bf16_to_f(hv.x));
        hv.y = bf16_rne(xr[1]); lv.y = bf16_rne(xr[1] - bf16_to_f(hv.y));
        hv.z = bf16_rne(xr[2]); lv.z = bf16_rne(xr[2] - bf16_to_f(hv.z));
        hv.w = bf16_rne(xr[3]); lv.w = bf16_rne(xr[3] - bf16_to_f(hv.w));
        *(ushort4*)&sXH[n_ * WP + mi * 16 + q * 4] = hv;
        *(ushort4*)&sXL[n_ * WP + mi * 16 + q * 4] = lv;
    }
    __syncthreads();
    v8s xaH[4][2], xaL[4][2];
#pragma unroll
    for (int mi = 0; mi < 4; ++mi)
#pragma unroll
        for (int kc = 0; kc < 2; ++kc) {
            xaH[mi][kc] = *(const v8s*)&sXH[(mi * 16 + c) * WP + kc * 32 + q * 8];
            xaL[mi][kc] = *(const v8s*)&sXL[(mi * 16 + c) * WP + kc * 32 + q * 8];
        }

#pragma unroll
    for (int j = 2; j <= D_CH; ++j) {
        const unsigned short* sH =
            (j == 2) ? &sXH[(wid * 16) * WP] : &sTH[((((j - 1) & 1)) * 4 + wid) * 16 * WP];
        const unsigned short* sL =
            (j == 2) ? &sXL[(wid * 16) * WP] : &sTL[((((j - 1) & 1)) * 4 + wid) * 16 * WP];
        unsigned short* dH = &sTH[((j & 1) * 4 + wid) * 16 * WP];
        unsigned short* dL = &sTL[((j & 1) * 4 + wid) * 16 * WP];
        v8s tbH[2], tbL[2];
#pragma unroll
        for (int kc = 0; kc < 2; ++kc) {
            tbH[kc] = *(const v8s*)&sH[c * WP + kc * 32 + q * 8];
            tbL[kc] = *(const v8s*)&sL[c * WP + kc * 32 + q * 8];
        }
#pragma unroll
        for (int mi = 0; mi < 4; ++mi) {
            v4f gt = (v4f){0.f, 0.f, 0.f, 0.f};
#pragma unroll
            for (int kc = 0; kc < 2; ++kc) {
                gt = __builtin_amdgcn_mfma_f32_16x16x32_bf16(xaH[mi][kc], tbH[kc], gt, 0, 0, 0);
                gt = __builtin_amdgcn_mfma_f32_16x16x32_bf16(xaH[mi][kc], tbL[kc], gt, 0, 0, 0);
                gt = __builtin_amdgcn_mfma_f32_16x16x32_bf16(xaL[mi][kc], tbH[kc], gt, 0, 0, 0);
            }
            v4f tn = 2.f * gt - Told[mi];
            Told[mi] = Tcur[mi];
            Tcur[mi] = tn;
            Facc[mi] += cf.cF[j] * tn;
            Qacc[mi] += cf.cQ[j] * tn;
            ushort4 hv, lv;
            hv.x = bf16_rne(tn[0]); lv.x = bf16_rne(tn[0] - bf16_to_f(hv.x));
            hv.y = bf16_rne(tn[1]); lv.y = bf16_rne(tn[1] - bf16_to_f(hv.y));
            hv.z = bf16_rne(tn[2]); lv.z = bf16_rne(tn[2] - bf16_to_f(hv.z));
            hv.w = bf16_rne(tn[3]); lv.w = bf16_rne(tn[3] - bf16_to_f(hv.w));
            *(ushort4*)&dH[c * WP + mi * 16 + q * 4] = hv;
            *(ushort4*)&dL[c * WP + mi * 16 + q * 4] = lv;
        }
    }

    unsigned short* fH = &sTH[(4 + wid) * 16 * WP];
    unsigned short* fL = &sTL[(4 + wid) * 16 * WP];
#pragma unroll
    for (int mi = 0; mi < 4; ++mi) {
        ushort4 hv, lv;
        hv.x = bf16_rne(Facc[mi][0]); lv.x = bf16_rne(Facc[mi][0] - bf16_to_f(hv.x));
        hv.y = bf16_rne(Facc[mi][1]); lv.y = bf16_rne(Facc[mi][1] - bf16_to_f(hv.y));
        hv.z = bf16_rne(Facc[mi][2]); lv.z = bf16_rne(Facc[mi][2] - bf16_to_f(hv.z));
        hv.w = bf16_rne(Facc[mi][3]); lv.w = bf16_rne(Facc[mi][3] - bf16_to_f(hv.w));
        *(ushort4*)&fH[c * WP + mi * 16 + q * 4] = hv;
        *(ushort4*)&fL[c * WP + mi * 16 + q * 4] = lv;
        *(v4f*)&ws[OFF_Q6 + (size_t)k * 4096 + n_ * 64 + mi * 16 + q * 4] = Qacc[mi];
    }

    {
        float p = 0.f;
        const int eb = q * 16;
        v8s h0 = *(const v8s*)&fH[c * WP + eb];
        v8s h1 = *(const v8s*)&fH[c * WP + eb + 8];
        v8s l0 = *(const v8s*)&fL[c * WP + eb];
        v8s l1 = *(const v8s*)&fL[c * WP + eb + 8];
#pragma unroll
        for (int jj = 0; jj < 8; ++jj) {
            p += (bf16_to_f((unsigned short)h0[jj]) + bf16_to_f((unsigned short)l0[jj])) * sV[eb + jj];
            p += (bf16_to_f((unsigned short)h1[jj]) + bf16_to_f((unsigned short)l1[jj])) * sV[eb + 8 + jj];
        }
        p += __shfl_xor(p, 16, 64);
        p += __shfl_xor(p, 32, 64);
        if (q == 0) ws[OFF_VT + (size_t)k * 64 + n_] = p;
    }

    v8s fbH[2], fbL[2];
#pragma unroll
    for (int kc = 0; kc < 2; ++kc) {
        fbH[kc] = *(const v8s*)&fH[c * WP + kc * 32 + q * 8];
        fbL[kc] = *(const v8s*)&fL[c * WP + kc * 32 + q * 8];
    }
    for (int rc = 0; rc < 4; ++rc) {
        __syncthreads();
#pragma unroll
        for (int i = 0; i < 4; ++i) {
            int lin = t + 256 * i;
            int g = lin >> 4, e4 = lin & 15;
            float4 x = *(const float4*)&w[((size_t)k * G_ + rc * 64 + g) * 64 + e4 * 4];
            ushort4 hv, lv;
            hv.x = bf16_rne(x.x); lv.x = bf16_rne(x.x - bf16_to_f(hv.x));
            hv.y = bf16_rne(x.y); lv.y = bf16_rne(x.y - bf16_to_f(hv.y));
            hv.z = bf16_rne(x.z); lv.z = bf16_rne(x.z - bf16_to_f(hv.z));
            hv.w = bf16_rne(x.w); lv.w = bf16_rne(x.w - bf16_to_f(hv.w));
            *(ushort4*)&sXH[g * WP + e4 * 4] = hv;
            *(ushort4*)&sXL[g * WP + e4 * 4] = lv;
        }
        __syncthreads();
#pragma unroll
        for (int mi = 0; mi < 4; ++mi) {
            v4f acc = (v4f){0.f, 0.f, 0.f, 0.f};
#pragma unroll
            for (int kc = 0; kc < 2; ++kc) {
                v8s aH = *(const v8s*)&sXH[(mi * 16 + c) * WP + kc * 32 + q * 8];
                v8s aL = *(const v8s*)&sXL[(mi * 16 + c) * WP + kc * 32 + q * 8];
                acc = __builtin_amdgcn_mfma_f32_16x16x32_bf16(aH, fbH[kc], acc, 0, 0, 0);
                acc = __builtin_amdgcn_mfma_f32_16x16x32_bf16(aH, fbL[kc], acc, 0, 0, 0);
                acc = __builtin_amdgcn_mfma_f32_16x16x32_bf16(aL, fbH[kc], acc, 0, 0, 0);
            }
            ushort4 hv, lv;
            hv.x = bf16_rne(acc[0]); lv.x = bf16_rne(acc[0] - bf16_to_f(hv.x));
            hv.y = bf16_rne(acc[1]); lv.y = bf16_rne(acc[1] - bf16_to_f(hv.y));
            hv.z = bf16_rne(acc[2]); lv.z = bf16_rne(acc[2] - bf16_to_f(hv.z));
            hv.w = bf16_rne(acc[3]); lv.w = bf16_rne(acc[3] - bf16_to_f(hv.w));
            size_t goff = ((size_t)k * 80 + n_) * 256 + rc * 64 + mi * 16 + q * 4;
            *(ushort4*)&wtTH[goff] = hv;
            *(ushort4*)&wtTL[goff] = lv;
        }
    }
}

// ---------------------------------------------------------------------------
// G1 v4: 256-row b-tiles. grid 1024, block 256 (4 waves, wave owns 64 rows =
// 4 m-tiles x 5 n-tiles = 60 MFMA/gc). XCD x (= id&7) owns k in [32x,32x+32).
// img + wt staged via LDS (load->store immediately — non-spilling shape).
// Scores transposed SCt[k][b], block-owned lines.
__global__ __launch_bounds__(256) void g1_kernel(float* __restrict__ ws) {
    const int L = blockIdx.x;
    const int xcdk = L & 7;
    const int rr = L >> 3;
    const int btile = rr & 3;
    const int klow = rr >> 2;
    const int k = xcdk * 32 + klow;
    const int b0 = btile * 256;
    const int t = threadIdx.x;
    const int wid = t >> 6, lane = t & 63;
    const int c = lane & 15, q = lane >> 4;
    __shared__ __align__(16) unsigned short sIH[256 * LP];
    __shared__ __align__(16) unsigned short sIL[256 * LP];
    __shared__ __align__(16) unsigned short sWH[80 * LP];
    __shared__ __align__(16) unsigned short sWL[80 * LP];
    __shared__ float sSC[256];

    const unsigned short* wsu = (const unsigned short*)(ws + OFF_U16);
    const unsigned short* wtTH = wsu + U_WTH;
    const unsigned short* wtTL = wsu + U_WTL;
    const unsigned short* imgH = wsu + U_IMGH;
    const unsigned short* imgL = wsu + U_IMGL;

    v4f acc[4][5];
#pragma unroll
    for (int mt = 0; mt < 4; ++mt)
#pragma unroll
        for (int nt = 0; nt < 5; ++nt) acc[mt][nt] = (v4f){0.f, 0.f, 0.f, 0.f};

    for (int gc = 0; gc < 8; ++gc) {
        __syncthreads();
        // img staging: 256 rows x 4 segs = 1024 (r,seg) pairs, both planes
#pragma unroll
        for (int i = 0; i < 4; ++i) {
            int idx = t + 256 * i;
            int r = idx >> 2, seg = idx & 3;
            size_t gsrc = (size_t)(b0 + r) * 256 + gc * 32 + seg * 8;
            *(uint4*)&sIH[r * LP + seg * 8] = *(const uint4*)&imgH[gsrc];
            *(uint4*)&sIL[r * LP + seg * 8] = *(const uint4*)&imgL[gsrc];
        }
        // wt staging: 80 cols x 4 segs = 320 pairs, both planes
        {
            int col = t >> 2, seg = t & 3;
            size_t gsrc = ((size_t)k * 80 + col) * 256 + gc * 32 + seg * 8;
            *(uint4*)&sWH[col * LP + seg * 8] = *(const uint4*)&wtTH[gsrc];
            *(uint4*)&sWL[col * LP + seg * 8] = *(const uint4*)&wtTL[gsrc];
            if (t < 64) {
                int idx = t + 256;
                int col2 = idx >> 2, seg2 = idx & 3;
                size_t g2 = ((size_t)k * 80 + col2) * 256 + gc * 32 + seg2 * 8;
                *(uint4*)&sWH[col2 * LP + seg2 * 8] = *(const uint4*)&wtTH[g2];
                *(uint4*)&sWL[col2 * LP + seg2 * 8] = *(const uint4*)&wtTL[g2];
            }
        }
        __syncthreads();
        v8s aH[4], aL[4];
#pragma unroll
        for (int mt = 0; mt < 4; ++mt) {
            int row = wid * 64 + mt * 16 + c;
            aH[mt] = *(const v8s*)&sIH[row * LP + q * 8];
            aL[mt] = *(const v8s*)&sIL[row * LP + q * 8];
        }
#pragma unroll
        for (int nt = 0; nt < 5; ++nt) {
            int colr = nt * 16 + c;
            v8s bH = *(const v8s*)&sWH[colr * LP + q * 8];
            v8s bL = *(const v8s*)&sWL[colr * LP + q * 8];
#pragma unroll
            for (int mt = 0; mt < 4; ++mt) {
                acc[mt][nt] = __builtin_amdgcn_mfma_f32_16x16x32_bf16(aH[mt], bH, acc[mt][nt], 0, 0, 0);
                acc[mt][nt] = __builtin_amdgcn_mfma_f32_16x16x32_bf16(aH[mt], bL, acc[mt][nt], 0, 0, 0);
                acc[mt][nt] = __builtin_amdgcn_mfma_f32_16x16x32_bf16(aL[mt], bH, acc[mt][nt], 0, 0, 0);
            }
        }
    }
    // epilogue: C layout col=lane&15, row=q*4+r
    float msq = ws[OFF_MSQ + k];
    float vtr[4];
#pragma unroll
    for (int nt = 0; nt < 4; ++nt)
        vtr[nt] = ws[OFF_VT + (size_t)k * 64 + nt * 16 + c];
#pragma unroll
    for (int mt = 0; mt < 4; ++mt) {
        float tot[4];
#pragma unroll
        for (int r = 0; r < 4; ++r) tot[r] = 0.f;
#pragma unroll
        for (int nt = 0; nt < 4; ++nt)
#pragma unroll
            for (int r = 0; r < 4; ++r) {
                float d = acc[mt][nt][r] - vtr[nt];
                tot[r] += d * d;
            }
        if (c == 0) {
#pragma unroll
            for (int r = 0; r < 4; ++r) tot[r] += 2.f * acc[mt][4][r];
        }
#pragma unroll
        for (int r = 0; r < 4; ++r) {
            tot[r] += __shfl_xor(tot[r], 1, 64);
            tot[r] += __shfl_xor(tot[r], 2, 64);
            tot[r] += __shfl_xor(tot[r], 4, 64);
            tot[r] += __shfl_xor(tot[r], 8, 64);
        }
        if (c == 0) {
#pragma unroll
            for (int r = 0; r < 4; ++r)
                sSC[wid * 64 + mt * 16 + q * 4 + r] = msq - tot[r];
        }
    }
    __syncthreads();
    if (t < 64) {
        float4 v = *(const float4*)&sSC[t * 4];
        *(float4*)&ws[OFF_SC + (size_t)k * B_ + b0 + t * 4] = v;
    }
}

// ---------------------------------------------------------------------------
// G2: per b: argmin_k of SCt[k][b], then u = W_k^T img - v ; z6 = Q6 u ;
// y = W_k z6 + m_k. [round-13 version, unchanged]
__global__ __launch_bounds__(256) void g2_kernel(const float* __restrict__ img,
                                                 const float* __restrict__ w,
                                                 const float* __restrict__ ws,
                                                 float* __restrict__ out) {
    const int b = blockIdx.x;
    const int t = threadIdx.x;
    const int wid = t >> 6, lane = t & 63;
    __shared__ float rv[4];
    __shared__ int ri[4];
    __shared__ int skbest;
    __shared__ float simg[256];
    __shared__ float up[4][64];
    __shared__ float su[64];
    __shared__ __align__(16) float sz[64];
    __shared__ float yrow[256];

    const unsigned short* wsu = (const unsigned short*)(ws + OFF_U16);
    const unsigned short* wtTH = wsu + U_WTH;
    const unsigned short* wtTL = wsu + U_WTL;

    float val = ws[OFF_SC + (size_t)t * B_ + b];
    int idx = t;
#pragma unroll
    for (int off = 32; off >= 1; off >>= 1) {
        float ov = __shfl_down(val, off, 64);
        int oi = __shfl_down(idx, off, 64);
        if (ov < val || (ov == val && oi < idx)) { val = ov; idx = oi; }
    }
    if ((t & 63) == 0) { rv[t >> 6] = val; ri[t >> 6] = idx; }
    simg[t] = img[(size_t)b * G_ + t];
    __syncthreads();
    if (t == 0) {
        float bv = rv[0]; int bi = ri[0];
#pragma unroll
        for (int i = 1; i < 4; ++i)
            if (rv[i] < bv || (rv[i] == bv && ri[i] < bi)) { bv = rv[i]; bi = ri[i]; }
        skbest = bi;
    }
    __syncthreads();
    const int kb = skbest;
    const int e = t & 63, p = t >> 6;

    {
        float acc = 0.f;
        const float* wcol = w + ((size_t)kb * G_ + p * 64) * E_ + e;
        for (int g = 0; g < 64; ++g) acc += wcol[(size_t)g * E_] * simg[p * 64 + g];
        up[p][e] = acc;
    }
    __syncthreads();
    if (t < 64)
        su[t] = up[0][t] + up[1][t] + up[2][t] + up[3][t] - ws[OFF_V + (size_t)kb * 64 + t];
    __syncthreads();
    {
        float acc = 0.f;
        const float* qrow = ws + OFF_Q6 + (size_t)kb * 4096 + e * 64 + p * 16;
#pragma unroll
        for (int f = 0; f < 16; ++f) acc += qrow[f] * su[p * 16 + f];
        up[p][e] = acc;
    }
    __syncthreads();
    if (t < 64) sz[t] = up[0][t] + up[1][t] + up[2][t] + up[3][t];
    __syncthreads();
    {
        const int j = lane & 15, rquad = lane >> 4;
        float4 zv = *(const float4*)&sz[j * 4];
#pragma unroll
        for (int sub = 0; sub < 16; ++sub) {
            int row = wid * 64 + sub * 4 + rquad;
            float4 wv = *(const float4*)&w[((size_t)kb * G_ + row) * 64 + j * 4];
            float p2 = wv.x * zv.x + wv.y * zv.y + wv.z * zv.z + wv.w * zv.w;
            p2 += __shfl_xor(p2, 1, 64);
            p2 += __shfl_xor(p2, 2, 64);
            p2 += __shfl_xor(p2, 4, 64);
            p2 += __shfl_xor(p2, 8, 64);
            if (j == 0) yrow[row] = p2;
        }
    }
    __syncthreads();
    {
        size_t mcol = ((size_t)kb * 80 + 64) * 256 + t;
        float m = bf16_to_f(wtTH[mcol]) + bf16_to_f(wtTL[mcol]);
        out[(size_t)b * G_ + t] = yrow[t] + m;
    }
}

// ---------------------------------------------------------------------------
extern "C" void kernel_launch(void* const* d_in, const int* in_sizes, int n_in,
                              void* d_out, int out_size, void* d_ws, size_t ws_size,
                              hipStream_t stream) {
    const float* img = (const float*)d_in[0];
    const float* mu  = (const float*)d_in[1];
    const float* w   = (const float*)d_in[2];
    float* out = (float*)d_out;
    float* ws = (float*)d_ws;

    const double aa = 0.06, bb = 1.85;
    const int NN = 64;
    double fF[NN], fQ[NN];
    for (int i = 0; i < NN; ++i) {
        double x = cos(M_PI * (i + 0.5) / NN);
        double lam = 0.5 * (aa + bb) + 0.5 * (bb - aa) * x;
        double m = 0.95 - 0.05 * lam;
        double p5 = 0.0, pw = 1.0;
        for (int j = 0; j < 5; ++j) { p5 += pw; pw *= m; }
        double p6 = p5 + pw;
        double p = 2.0 * 0.05 * p5 - 0.05 * 0.05 * lam * p5 * p5;
        fF[i] = sqrt(p);
        fQ[i] = 0.05 * p6;
    }
    Cheb cf;
    for (int j = 0; j <= D_CH; ++j) {
        double sF = 0.0, sQ = 0.0;
        for (int i = 0; i < NN; ++i) {
            double cw = cos(M_PI * j * (i + 0.5) / NN);
            sF += fF[i] * cw;
            sQ += fQ[i] * cw;
        }
        double sc = 2.0 / NN;
        if (j == 0) sc *= 0.5;
        cf.cF[j] = (float)(sF * sc);
        cf.cQ[j] = (float)(sQ * sc);
    }
    cf.alpha = (float)(2.0 / (bb - aa));
    cf.gamma = (float)(-(bb + aa) / (bb - aa));

    hipLaunchKernelGGL(pre_kernel, dim3(K_), dim3(256), 0, stream, img, w, mu, ws, cf);
    hipLaunchKernelGGL(g1_kernel, dim3(1024), dim3(256), 0, stream, ws);
    hipLaunchKernelGGL(g2_kernel, dim3(B_), dim3(256), 0, stream, img, w, ws, out);
}